// Round 2
// baseline (8448.544 us; speedup 1.0000x reference)
//
#include <hip/hip_runtime.h>
#include <hip/hip_bf16.h>

using bf16 = __hip_bfloat16;
using bf16x2 = __hip_bfloat162;

static __device__ __forceinline__ float b2f(bf16 v){ return __bfloat162float(v); }
static __device__ __forceinline__ bf16  f2b(float v){ return __float2bfloat16(v); }
static __device__ __forceinline__ float2 ld2(const bf16* p){
  return __bfloat1622float2(*reinterpret_cast<const bf16x2*>(p));
}

// geometry (hard-coded for this problem instance)
constexpr int TPB  = 256;
constexpr int C    = 96;
constexpr int NT   = 64;     // tokens per 8x8 window
constexpr int HID  = 192;
constexpr float EPS = 1e-5f;
constexpr float QSC = 0.17677669529663687f;   // 32^-0.5

// ---- bf16 parameter pack layout in d_ws (element offsets; weight rows even-aligned)
constexpr int P_QKVW = 0;        // 27648
constexpr int P_QKVB = 27648;    // 288
constexpr int P_PROJW= 27936;    // 9216
constexpr int P_PROJB= 37152;    // 96
constexpr int P_RPB  = 37248;    // 675
constexpr int P_N1G  = 37924;    // 96
constexpr int P_N1B  = 38020;    // 96
constexpr int P_N2G  = 38116;    // 96
constexpr int P_N2B  = 38212;    // 96
constexpr int P_FC1W = 38308;    // 18432
constexpr int P_FC1B = 56740;    // 192
constexpr int P_FC2W = 56932;    // 18432
constexpr int P_FC2B = 75364;    // 96
constexpr int P_TOTAL= 75460;    // elements (bf16) -> 150,920 bytes

// LDS row strides (bf16 elements) — padded to avoid 32-bank conflicts
constexpr int SLN = 98;    // [64][96] bf16
constexpr int SAO = 98;
constexpr int SQK = 34;    // q/k/v [64][32]
constexpr int SP  = 66;    // P [64][64] bf16
constexpr int SSC = 65;    // scores [64][64] fp32
constexpr int SH  = 194;   // fc1 out [64][192]

constexpr int OFF_LN  = 0;                     // 12544 B
constexpr int OFF_AO  = 12544;                 // 12544 B
constexpr int OFF_QKV = 25088;                 // 13056 B (3x 64*34*2)
constexpr int OFF_SC  = 25088 + 13056;         // 16640 B (64*65*4)
constexpr int OFF_H   = 25088;                 // aliases qkv+scores in MLP stage (24832 B)
constexpr int SMEM_BYTES = 25088 + 13056 + 16640;  // 54784

// ---------------------------------------------------------------- param convert
struct ParamSrc { const float* p[13]; };

__global__ __launch_bounds__(256) void convert_params_kernel(ParamSrc ps, bf16* ws){
  constexpr int len [13] = {27648,288,9216,96,675,96,96,96,96,18432,192,18432,96};
  constexpr int woff[13] = {P_QKVW,P_QKVB,P_PROJW,P_PROJB,P_RPB,
                            P_N1G,P_N1B,P_N2G,P_N2B,P_FC1W,P_FC1B,P_FC2W,P_FC2B};
  int i = blockIdx.x * 256 + threadIdx.x;   // linear over concatenated params
  int s = 0;
  #pragma unroll
  for (int t = 0; t < 13; t++){
    if (i >= len[t]) { i -= len[t]; s++; }
    else break;
  }
  if (s < 13) ws[woff[s] + i] = f2b(ps.p[s][i]);
}

// ---------------------------------------------------------------- main kernel
__global__ __launch_bounds__(TPB) void swin_block_kernel(
    const float* __restrict__ x,
    const bf16* __restrict__ wsp,      // bf16 param pack
    float* __restrict__ out)
{
  __shared__ alignas(16) unsigned char smem[SMEM_BYTES];
  bf16*  s_ln = (bf16*)(smem + OFF_LN);   // x -> ln1 out; later proj out -> ln2 out
  bf16*  s_ao = (bf16*)(smem + OFF_AO);   // attn out; later block output (pre-residual)
  bf16*  s_q  = (bf16*)(smem + OFF_QKV);
  bf16*  s_k  = s_q + NT*SQK;
  bf16*  s_v  = s_k + NT*SQK;
  bf16*  s_p  = s_q;                      // P aliases q+k after they die
  float* s_sc = (float*)(smem + OFF_SC);
  bf16*  s_h  = (bf16*)(smem + OFF_H);

  const bf16* qkv_w  = wsp + P_QKVW;
  const bf16* qkv_b  = wsp + P_QKVB;
  const bf16* proj_w = wsp + P_PROJW;
  const bf16* proj_b = wsp + P_PROJB;
  const bf16* rpb    = wsp + P_RPB;
  const bf16* n1g    = wsp + P_N1G;
  const bf16* n1b    = wsp + P_N1B;
  const bf16* n2g    = wsp + P_N2G;
  const bf16* n2b    = wsp + P_N2B;
  const bf16* fc1w   = wsp + P_FC1W;
  const bf16* fc1b   = wsp + P_FC1B;
  const bf16* fc2w   = wsp + P_FC2W;
  const bf16* fc2b   = wsp + P_FC2B;

  const int tid = threadIdx.x;
  const int blk = blockIdx.x;
  const int b  = blk >> 10;          // batch
  const int wh = (blk >> 5) & 31;    // window row
  const int ww = blk & 31;           // window col
  const size_t base = ((size_t)b * C) * 65536 + (size_t)wh * 2048 + (size_t)ww * 8;
  // element (c, i, j) of this window lives at base + c*65536 + i*256 + j

  // ---------------- stage 0: load x window, convert to bf16 ----
  for (int idx = tid; idx < NT*C; idx += TPB) {
    const int c = idx >> 6, n = idx & 63;
    s_ln[n*SLN + c] = f2b(x[base + (size_t)c*65536 + (n>>3)*256 + (n&7)]);
  }
  __syncthreads();

  // ---------------- LN1 (in place; one thread per token) ----
  if (tid < NT) {
    bf16* row = s_ln + tid*SLN;
    float sum = 0.f, sq = 0.f;
    for (int c = 0; c < C; c++){ float v = b2f(row[c]); sum += v; sq += v*v; }
    const float mu  = sum * (1.f/96.f);
    const float inv = rsqrtf(fmaxf(sq*(1.f/96.f) - mu*mu, 0.f) + EPS);
    for (int c = 0; c < C; c++)
      row[c] = f2b((b2f(row[c]) - mu) * inv * b2f(n1g[c]) + b2f(n1b[c]));
  }
  __syncthreads();

  // ---------------- attention, one head at a time ----
  for (int h = 0; h < 3; h++) {
    // ---- qkv for head h: 64 rows x 96 cols (s in {q,k,v} x d in [0,32)), K=96
    {
      const int tr = tid >> 4, tc = tid & 15;   // 16x16 grid of 4x6 tiles
      const int n0 = tr*4, o0 = tc*6;
      int og[6]; const bf16* wp[6];
      #pragma unroll
      for (int j = 0; j < 6; j++){
        const int o = o0 + j;
        og[j] = ((o>>5)*3 + h)*32 + (o&31);     // row in qkv_w (288x96)
        wp[j] = qkv_w + og[j]*C;
      }
      float acc[4][6] = {};
      for (int c = 0; c < C; c += 2){
        float2 a[4], wv[6];
        #pragma unroll
        for (int i = 0; i < 4; i++) a[i] = ld2(&s_ln[(n0+i)*SLN + c]);
        #pragma unroll
        for (int j = 0; j < 6; j++) wv[j] = ld2(wp[j] + c);
        #pragma unroll
        for (int i = 0; i < 4; i++)
          #pragma unroll
          for (int j = 0; j < 6; j++)
            acc[i][j] += a[i].x*wv[j].x + a[i].y*wv[j].y;
      }
      #pragma unroll
      for (int j = 0; j < 6; j++){
        const int o = o0 + j, s = o >> 5, d = o & 31;
        const float bias = b2f(qkv_b[og[j]]);
        const float scl  = (s == 0) ? QSC : 1.f;
        bf16* dst = s_q + s*(NT*SQK);
        #pragma unroll
        for (int i = 0; i < 4; i++)
          dst[(n0+i)*SQK + d] = f2b((acc[i][j] + bias) * scl);
      }
    }
    __syncthreads();

    // ---- scores S = q k^T + rel-pos bias : 64x64, K=32 (fp32 in LDS)
    {
      const int tr = tid >> 4, tc = tid & 15;   // 16x16 grid of 4x4 tiles
      const int n0 = tr*4, m0 = tc*4;
      float acc[4][4] = {};
      for (int d = 0; d < 32; d += 2){
        float2 q[4], k[4];
        #pragma unroll
        for (int i = 0; i < 4; i++) q[i] = ld2(&s_q[(n0+i)*SQK + d]);
        #pragma unroll
        for (int j = 0; j < 4; j++) k[j] = ld2(&s_k[(m0+j)*SQK + d]);
        #pragma unroll
        for (int i = 0; i < 4; i++)
          #pragma unroll
          for (int j = 0; j < 4; j++)
            acc[i][j] += q[i].x*k[j].x + q[i].y*k[j].y;
      }
      #pragma unroll
      for (int i = 0; i < 4; i++)
        #pragma unroll
        for (int j = 0; j < 4; j++){
          const int n = n0+i, m = m0+j;
          const int rel = ((n>>3)-(m>>3)+7)*15 + ((n&7)-(m&7)+7);
          s_sc[n*SSC + m] = acc[i][j] + b2f(rpb[rel*3 + h]);
        }
    }
    __syncthreads();

    // ---- softmax rows -> P (bf16, into dead q+k region)
    if (tid < NT){
      float* r = s_sc + tid*SSC;
      float mx = r[0];
      for (int m = 1; m < 64; m++) mx = fmaxf(mx, r[m]);
      float sum = 0.f;
      for (int m = 0; m < 64; m++){ float e = __expf(r[m]-mx); sum += e; r[m] = e; }
      const float rs = 1.f/sum;
      bf16* pr = s_p + tid*SP;
      for (int m = 0; m < 64; m++) pr[m] = f2b(r[m]*rs);
    }
    __syncthreads();

    // ---- out_h = P @ V : 64x32, K=64 -> s_ao[:, h*32 : h*32+32]
    {
      const int n0 = (tid >> 3)*2, d0 = (tid & 7)*4;  // 32x8 grid of 2x4 tiles
      float acc[2][4] = {};
      for (int m = 0; m < 64; m += 2){
        const float2 p0 = ld2(&s_p[ n0   *SP + m]);
        const float2 p1 = ld2(&s_p[(n0+1)*SP + m]);
        const float2 va = ld2(&s_v[ m   *SQK + d0]);
        const float2 vb = ld2(&s_v[ m   *SQK + d0+2]);
        const float2 vc = ld2(&s_v[(m+1)*SQK + d0]);
        const float2 vd = ld2(&s_v[(m+1)*SQK + d0+2]);
        acc[0][0] += p0.x*va.x + p0.y*vc.x;
        acc[0][1] += p0.x*va.y + p0.y*vc.y;
        acc[0][2] += p0.x*vb.x + p0.y*vd.x;
        acc[0][3] += p0.x*vb.y + p0.y*vd.y;
        acc[1][0] += p1.x*va.x + p1.y*vc.x;
        acc[1][1] += p1.x*va.y + p1.y*vc.y;
        acc[1][2] += p1.x*vb.x + p1.y*vd.x;
        acc[1][3] += p1.x*vb.y + p1.y*vd.y;
      }
      #pragma unroll
      for (int i = 0; i < 2; i++)
        #pragma unroll
        for (int j = 0; j < 4; j++)
          s_ao[(n0+i)*SAO + h*32 + d0 + j] = f2b(acc[i][j]);
    }
    __syncthreads();
  }

  // ---------------- proj: 64x96, K=96 (A = s_ao, out -> s_ln; ln1 data is dead)
  {
    const int tr = tid >> 4, tc = tid & 15;
    const int n0 = tr*4, o0 = tc*6;
    float acc[4][6] = {};
    for (int c = 0; c < C; c += 2){
      float2 a[4], wv[6];
      #pragma unroll
      for (int i = 0; i < 4; i++) a[i] = ld2(&s_ao[(n0+i)*SAO + c]);
      #pragma unroll
      for (int j = 0; j < 6; j++) wv[j] = ld2(&proj_w[(o0+j)*C + c]);
      #pragma unroll
      for (int i = 0; i < 4; i++)
        #pragma unroll
        for (int j = 0; j < 6; j++)
          acc[i][j] += a[i].x*wv[j].x + a[i].y*wv[j].y;
    }
    #pragma unroll
    for (int j = 0; j < 6; j++){
      const float bias = b2f(proj_b[o0+j]);
      #pragma unroll
      for (int i = 0; i < 4; i++)
        s_ln[(n0+i)*SLN + o0 + j] = f2b(acc[i][j] + bias);
    }
  }
  __syncthreads();

  // ---------------- LN2 in place on s_ln ----
  if (tid < NT) {
    bf16* row = s_ln + tid*SLN;
    float sum = 0.f, sq = 0.f;
    for (int c = 0; c < C; c++){ float v = b2f(row[c]); sum += v; sq += v*v; }
    const float mu  = sum * (1.f/96.f);
    const float inv = rsqrtf(fmaxf(sq*(1.f/96.f) - mu*mu, 0.f) + EPS);
    for (int c = 0; c < C; c++)
      row[c] = f2b((b2f(row[c]) - mu) * inv * b2f(n2g[c]) + b2f(n2b[c]));
  }
  __syncthreads();

  // ---------------- fc1 + exact GELU: 64x192, K=96 -> s_h
  for (int t = tid; t < 512; t += TPB){    // 16x32 grid of 4x6 tiles
    const int tr = t >> 5, tc = t & 31;
    const int n0 = tr*4, o0 = tc*6;
    float acc[4][6] = {};
    for (int c = 0; c < C; c += 2){
      float2 a[4], wv[6];
      #pragma unroll
      for (int i = 0; i < 4; i++) a[i] = ld2(&s_ln[(n0+i)*SLN + c]);
      #pragma unroll
      for (int j = 0; j < 6; j++) wv[j] = ld2(&fc1w[(o0+j)*C + c]);
      #pragma unroll
      for (int i = 0; i < 4; i++)
        #pragma unroll
        for (int j = 0; j < 6; j++)
          acc[i][j] += a[i].x*wv[j].x + a[i].y*wv[j].y;
    }
    #pragma unroll
    for (int j = 0; j < 6; j++){
      const float bias = b2f(fc1b[o0+j]);
      #pragma unroll
      for (int i = 0; i < 4; i++){
        const float v = acc[i][j] + bias;
        const float g = 0.5f * v * (1.f + erff(v * 0.70710678118654752f));
        s_h[(n0+i)*SH + o0 + j] = f2b(g);
      }
    }
  }
  __syncthreads();

  // ---------------- fc2: 64x96, K=192 -> s_ao (block output, pre-residual)
  {
    const int tr = tid >> 4, tc = tid & 15;
    const int n0 = tr*4, o0 = tc*6;
    float acc[4][6] = {};
    for (int c = 0; c < HID; c += 2){
      float2 a[4], wv[6];
      #pragma unroll
      for (int i = 0; i < 4; i++) a[i] = ld2(&s_h[(n0+i)*SH + c]);
      #pragma unroll
      for (int j = 0; j < 6; j++) wv[j] = ld2(&fc2w[(o0+j)*HID + c]);
      #pragma unroll
      for (int i = 0; i < 4; i++)
        #pragma unroll
        for (int j = 0; j < 6; j++)
          acc[i][j] += a[i].x*wv[j].x + a[i].y*wv[j].y;
    }
    #pragma unroll
    for (int j = 0; j < 6; j++){
      const float bias = b2f(fc2b[o0+j]);
      #pragma unroll
      for (int i = 0; i < 4; i++)
        s_ao[(n0+i)*SAO + o0 + j] = f2b(acc[i][j] + bias);
    }
  }
  __syncthreads();

  // ---------------- write-out: fp32 residual add (re-read x), window merge
  for (int idx = tid; idx < NT*C; idx += TPB){
    const int c = idx >> 6, n = idx & 63;
    const size_t g = base + (size_t)c*65536 + (n>>3)*256 + (n&7);
    out[g] = x[g] + b2f(s_ao[n*SAO + c]);
  }
}

extern "C" void kernel_launch(void* const* d_in, const int* in_sizes, int n_in,
                              void* d_out, int out_size, void* d_ws, size_t ws_size,
                              hipStream_t stream) {
  const float* x = (const float*)d_in[0];
  ParamSrc ps;
  ps.p[0]  = (const float*)d_in[1];   // qkv_w
  ps.p[1]  = (const float*)d_in[2];   // qkv_b
  ps.p[2]  = (const float*)d_in[3];   // proj_w
  ps.p[3]  = (const float*)d_in[4];   // proj_b
  ps.p[4]  = (const float*)d_in[5];   // rpb_table
  ps.p[5]  = (const float*)d_in[6];   // norm1_g
  ps.p[6]  = (const float*)d_in[7];   // norm1_b
  ps.p[7]  = (const float*)d_in[8];   // norm2_g
  ps.p[8]  = (const float*)d_in[9];   // norm2_b
  ps.p[9]  = (const float*)d_in[10];  // fc1_w
  ps.p[10] = (const float*)d_in[11];  // fc1_b
  ps.p[11] = (const float*)d_in[12];  // fc2_w
  ps.p[12] = (const float*)d_in[13];  // fc2_b
  // d_in[14], d_in[15] are H, W (int scalars) — fixed at 256, hard-coded.
  bf16* wsp = (bf16*)d_ws;
  float* out = (float*)d_out;

  convert_params_kernel<<<dim3((75459 + 255)/256), dim3(256), 0, stream>>>(ps, wsp);
  swin_block_kernel<<<dim3(8192), dim3(TPB), 0, stream>>>(x, wsp, out);
}

// Round 4
// 1538.818 us; speedup vs baseline: 5.4903x; 5.4903x over previous
//
#include <hip/hip_runtime.h>
#include <hip/hip_bf16.h>

using bf16 = __hip_bfloat16;
typedef short short8  __attribute__((ext_vector_type(8)));   // 8 bf16 (4 VGPRs) MFMA frag
typedef short short4v __attribute__((ext_vector_type(4)));
typedef float f32x4   __attribute__((ext_vector_type(4)));   // MFMA accumulator

static __device__ __forceinline__ float b2f(bf16 v){ return __bfloat162float(v); }
static __device__ __forceinline__ bf16  f2b(float v){ return __float2bfloat16(v); }
static __device__ __forceinline__ float s2f(short s){ return __bfloat162float(__builtin_bit_cast(bf16, s)); }
static __device__ __forceinline__ short f2s(float f){ return __builtin_bit_cast(short, __float2bfloat16(f)); }

// load 8 consecutive fp32 weights -> bf16x8 MFMA fragment (on-the-fly convert; no d_ws)
static __device__ __forceinline__ short8 ldw8(const float* __restrict__ p){
  const float4 u = *(const float4*)(p);
  const float4 v = *(const float4*)(p + 4);
  short8 r;
  r[0]=f2s(u.x); r[1]=f2s(u.y); r[2]=f2s(u.z); r[3]=f2s(u.w);
  r[4]=f2s(v.x); r[5]=f2s(v.y); r[6]=f2s(v.z); r[7]=f2s(v.w);
  return r;
}

#define MFMA16(a,b,c) __builtin_amdgcn_mfma_f32_16x16x32_bf16((a),(b),(c),0,0,0)

constexpr int TPB = 256;
constexpr float EPS = 1e-5f;
constexpr float QSC = 0.17677669529663687f;   // 32^-0.5

// ---- LDS layout (byte offsets). All row strides multiples of 16B for b128 frag ops.
constexpr int A_OFF = 0;       // s_a  [64][104] bf16: x/ln1 -> proj-out/ln2; s_at [96][68] (fc2 out, transposed)
constexpr int B_OFF = 13312;   // s_ao [64][104] bf16: attn-out; s_h [64][200] (fc1 out) spans B..E
constexpr int C_OFF = 26624;   // q  [64][40]
constexpr int D_OFF = 31744;   // k  [64][40]
constexpr int E_OFF = 36864;   // vt [32][72]  (V^T: [d][token])
constexpr int F_OFF = 41472;   // P  [64][72]
constexpr int SMEM_BYTES = 50688;   // *3 = 152,064 <= 163,840 -> 3 blocks/CU

__global__ __launch_bounds__(TPB, 3) void swin_block_kernel(
    const float* __restrict__ x,
    const float* __restrict__ qkvw,  const float* __restrict__ qkvb,
    const float* __restrict__ projw, const float* __restrict__ projb,
    const float* __restrict__ rpb,
    const float* __restrict__ n1g,   const float* __restrict__ n1b,
    const float* __restrict__ n2g,   const float* __restrict__ n2b,
    const float* __restrict__ fc1w,  const float* __restrict__ fc1b,
    const float* __restrict__ fc2w,  const float* __restrict__ fc2b,
    float* __restrict__ out)
{
  __shared__ alignas(16) unsigned char smem[SMEM_BYTES];
  bf16* s_a  = (bf16*)(smem + A_OFF);   // stride 104
  bf16* s_ao = (bf16*)(smem + B_OFF);   // stride 104
  bf16* s_q  = (bf16*)(smem + C_OFF);   // stride 40
  bf16* s_k  = (bf16*)(smem + D_OFF);   // stride 40
  bf16* s_vt = (bf16*)(smem + E_OFF);   // stride 72
  bf16* s_p  = (bf16*)(smem + F_OFF);   // stride 72
  bf16* s_h  = (bf16*)(smem + B_OFF);   // stride 200 (fc1 out, spans B..E; vt/q/k dead there)
  bf16* s_at = (bf16*)(smem + A_OFF);   // stride 68  (fc2 out transposed [96][68])

  const int tid  = threadIdx.x;
  const int wid  = tid >> 6;
  const int lane = tid & 63;
  const int quad = lane >> 4;
  const int l15  = lane & 15;
  const int m0   = wid * 16;       // wave's m-tile rows [m0, m0+16)
  const int row0 = m0 + quad * 4;  // C/D frag rows row0..row0+3

  const int blk = blockIdx.x;
  const int b  = blk >> 10;
  const int wh = (blk >> 5) & 31;
  const int ww = blk & 31;
  const size_t base = ((size_t)b * 96) * 65536 + (size_t)wh * 2048 + (size_t)ww * 8;
  // element (c, i, j) of this window at base + c*65536 + i*256 + j ; token = i*8+j

  // ---------------- load x window (float4), scatter to token-major bf16 ----
  #pragma unroll
  for (int it = 0; it < 6; it++){
    const int idx4 = it*256 + tid;
    const int c = idx4 >> 4, r = idx4 & 15;
    const int irow = r >> 1, j0 = (r & 1) * 4;
    const int t0 = irow*8 + j0;
    const float4 xv = *(const float4*)(x + base + (size_t)c*65536 + irow*256 + j0);
    s_a[(t0+0)*104 + c] = f2b(xv.x);
    s_a[(t0+1)*104 + c] = f2b(xv.y);
    s_a[(t0+2)*104 + c] = f2b(xv.z);
    s_a[(t0+3)*104 + c] = f2b(xv.w);
  }
  __syncthreads();

  // ---------------- LN helper: 4 threads per row, shuffle combine (params fp32) ----
  auto layernorm = [&](bf16* buf, const float* g, const float* bta){
    const int r = tid >> 2, s = tid & 3;
    bf16* row = buf + r*104;
    const int cb = s*24;
    float vals[24];
    float sum = 0.f, sq = 0.f;
    #pragma unroll
    for (int u = 0; u < 3; u++){
      short8 v8 = *(const short8*)(row + cb + u*8);
      #pragma unroll
      for (int j = 0; j < 8; j++){ float f = s2f(v8[j]); vals[u*8+j] = f; sum += f; sq += f*f; }
    }
    sum += __shfl_xor(sum, 1); sum += __shfl_xor(sum, 2);
    sq  += __shfl_xor(sq , 1); sq  += __shfl_xor(sq , 2);
    const float mu  = sum * (1.f/96.f);
    const float inv = rsqrtf(fmaxf(sq*(1.f/96.f) - mu*mu, 0.f) + EPS);
    #pragma unroll
    for (int u = 0; u < 3; u++){
      const float4 g4a = *(const float4*)(g   + cb + u*8);
      const float4 g4b = *(const float4*)(g   + cb + u*8 + 4);
      const float4 b4a = *(const float4*)(bta + cb + u*8);
      const float4 b4b = *(const float4*)(bta + cb + u*8 + 4);
      short8 o8;
      o8[0] = f2s((vals[u*8+0] - mu) * inv * g4a.x + b4a.x);
      o8[1] = f2s((vals[u*8+1] - mu) * inv * g4a.y + b4a.y);
      o8[2] = f2s((vals[u*8+2] - mu) * inv * g4a.z + b4a.z);
      o8[3] = f2s((vals[u*8+3] - mu) * inv * g4a.w + b4a.w);
      o8[4] = f2s((vals[u*8+4] - mu) * inv * g4b.x + b4b.x);
      o8[5] = f2s((vals[u*8+5] - mu) * inv * g4b.y + b4b.y);
      o8[6] = f2s((vals[u*8+6] - mu) * inv * g4b.z + b4b.z);
      o8[7] = f2s((vals[u*8+7] - mu) * inv * g4b.w + b4b.w);
      *(short8*)(row + cb + u*8) = o8;
    }
  };

  layernorm(s_a, n1g, n1b);
  __syncthreads();

  const f32x4 zac = {0.f, 0.f, 0.f, 0.f};

  // ---------------- attention: head at a time ----
  for (int h = 0; h < 3; h++){
    // ---- qkv_h : M=64 (wave m-tile), N=96 (q|k|v x 32), K=96
    {
      const short8 a0 = *(const short8*)(s_a + (m0+l15)*104 +  0 + quad*8);
      const short8 a1 = *(const short8*)(s_a + (m0+l15)*104 + 32 + quad*8);
      const short8 a2 = *(const short8*)(s_a + (m0+l15)*104 + 64 + quad*8);
      #pragma unroll
      for (int nt = 0; nt < 6; nt++){
        const int sect = nt >> 1;                 // 0=q 1=k 2=v
        const int d = (nt & 1)*16 + l15;          // 0..31 within head
        const int wrow = sect*96 + h*32 + d;      // row of qkv_w (288x96)
        const float* wp = qkvw + wrow*96 + quad*8;
        f32x4 acc = zac;
        acc = MFMA16(a0, ldw8(wp +  0), acc);
        acc = MFMA16(a1, ldw8(wp + 32), acc);
        acc = MFMA16(a2, ldw8(wp + 64), acc);
        const float bias = qkvb[wrow];
        if (sect == 0){
          #pragma unroll
          for (int r = 0; r < 4; r++)
            s_q[(row0+r)*40 + d] = f2b((acc[r] + bias) * QSC);
        } else if (sect == 1){
          #pragma unroll
          for (int r = 0; r < 4; r++)
            s_k[(row0+r)*40 + d] = f2b(acc[r] + bias);
        } else {
          short4v pk;
          #pragma unroll
          for (int r = 0; r < 4; r++) pk[r] = f2s(acc[r] + bias);
          *(short4v*)(s_vt + d*72 + row0) = pk;   // V^T, 4 consecutive tokens
        }
      }
    }
    __syncthreads();

    // ---- scores S = q k^T (+rpb bias), register softmax -> P ----
    {
      const short8 aq = *(const short8*)(s_q + (m0+l15)*40 + quad*8);
      f32x4 sc[4];
      #pragma unroll
      for (int nt = 0; nt < 4; nt++){
        const short8 bk = *(const short8*)(s_k + (nt*16+l15)*40 + quad*8);
        sc[nt] = MFMA16(aq, bk, zac);
      }
      #pragma unroll
      for (int nt = 0; nt < 4; nt++){
        const int col = nt*16 + l15, ci = col >> 3, cj = col & 7;
        #pragma unroll
        for (int r = 0; r < 4; r++){
          const int row = row0 + r, ri = row >> 3, rj = row & 7;
          const int rel = (ri - ci + 7)*15 + (rj - cj + 7);
          sc[nt][r] += rpb[rel*3 + h];
        }
      }
      #pragma unroll
      for (int r = 0; r < 4; r++){
        float mx = fmaxf(fmaxf(sc[0][r], sc[1][r]), fmaxf(sc[2][r], sc[3][r]));
        mx = fmaxf(mx, __shfl_xor(mx, 1));
        mx = fmaxf(mx, __shfl_xor(mx, 2));
        mx = fmaxf(mx, __shfl_xor(mx, 4));
        mx = fmaxf(mx, __shfl_xor(mx, 8));
        const float e0 = __expf(sc[0][r]-mx), e1 = __expf(sc[1][r]-mx);
        const float e2 = __expf(sc[2][r]-mx), e3 = __expf(sc[3][r]-mx);
        float sm = e0+e1+e2+e3;
        sm += __shfl_xor(sm, 1);
        sm += __shfl_xor(sm, 2);
        sm += __shfl_xor(sm, 4);
        sm += __shfl_xor(sm, 8);
        const float rs = 1.f / sm;
        const int prow = (row0 + r)*72;
        s_p[prow +  0 + l15] = f2b(e0*rs);
        s_p[prow + 16 + l15] = f2b(e1*rs);
        s_p[prow + 32 + l15] = f2b(e2*rs);
        s_p[prow + 48 + l15] = f2b(e3*rs);
      }
    }
    __syncthreads();

    // ---- PV : M=64, N=32, K=64 -> ao[:, h*32 + d] ----
    {
      const short8 p0 = *(const short8*)(s_p + (m0+l15)*72 +  0 + quad*8);
      const short8 p1 = *(const short8*)(s_p + (m0+l15)*72 + 32 + quad*8);
      #pragma unroll
      for (int nt = 0; nt < 2; nt++){
        f32x4 acc = zac;
        acc = MFMA16(p0, *(const short8*)(s_vt + (nt*16+l15)*72 +  0 + quad*8), acc);
        acc = MFMA16(p1, *(const short8*)(s_vt + (nt*16+l15)*72 + 32 + quad*8), acc);
        #pragma unroll
        for (int r = 0; r < 4; r++)
          s_ao[(row0+r)*104 + h*32 + nt*16 + l15] = f2b(acc[r]);
      }
    }
    __syncthreads();
  }

  // ---------------- proj: M=64, N=96, K=96 (A=s_ao -> s_a) ----
  {
    const short8 a0 = *(const short8*)(s_ao + (m0+l15)*104 +  0 + quad*8);
    const short8 a1 = *(const short8*)(s_ao + (m0+l15)*104 + 32 + quad*8);
    const short8 a2 = *(const short8*)(s_ao + (m0+l15)*104 + 64 + quad*8);
    #pragma unroll
    for (int nt = 0; nt < 6; nt++){
      const int wrow = nt*16 + l15;
      const float* wp = projw + wrow*96 + quad*8;
      f32x4 acc = zac;
      acc = MFMA16(a0, ldw8(wp +  0), acc);
      acc = MFMA16(a1, ldw8(wp + 32), acc);
      acc = MFMA16(a2, ldw8(wp + 64), acc);
      const float bias = projb[wrow];
      #pragma unroll
      for (int r = 0; r < 4; r++)
        s_a[(row0+r)*104 + wrow] = f2b(acc[r] + bias);
    }
  }
  __syncthreads();

  // ---------------- LN2 in place on s_a ----
  layernorm(s_a, n2g, n2b);
  __syncthreads();

  // ---------------- fc1 + GELU: M=64, N=192, K=96 -> s_h[64][200] ----
  {
    const short8 a0 = *(const short8*)(s_a + (m0+l15)*104 +  0 + quad*8);
    const short8 a1 = *(const short8*)(s_a + (m0+l15)*104 + 32 + quad*8);
    const short8 a2 = *(const short8*)(s_a + (m0+l15)*104 + 64 + quad*8);
    #pragma unroll
    for (int nt = 0; nt < 12; nt++){
      const int wrow = nt*16 + l15;
      const float* wp = fc1w + wrow*96 + quad*8;
      f32x4 acc = zac;
      acc = MFMA16(a0, ldw8(wp +  0), acc);
      acc = MFMA16(a1, ldw8(wp + 32), acc);
      acc = MFMA16(a2, ldw8(wp + 64), acc);
      const float bias = fc1b[wrow];
      #pragma unroll
      for (int r = 0; r < 4; r++){
        const float v = acc[r] + bias;
        // GELU via tanh identity: g = v - v/(e^{2y}+1), y = 0.7978845608*(v+0.044715 v^3)
        const float t = __expf(1.5957691216057308f * (v + 0.044715f*v*v*v));
        const float g = v - v * (1.f / (t + 1.f));
        s_h[(row0+r)*200 + wrow] = f2b(g);
      }
    }
  }
  __syncthreads();

  // ---------------- fc2: M=64, N=96, K=192 -> s_at transposed [96][68] ----
  {
    short8 a[6];
    #pragma unroll
    for (int ks = 0; ks < 6; ks++)
      a[ks] = *(const short8*)(s_h + (m0+l15)*200 + ks*32 + quad*8);
    #pragma unroll
    for (int nt = 0; nt < 6; nt++){
      const int wrow = nt*16 + l15;
      const float* wp = fc2w + wrow*192 + quad*8;
      f32x4 acc = zac;
      #pragma unroll
      for (int ks = 0; ks < 6; ks++)
        acc = MFMA16(a[ks], ldw8(wp + ks*32), acc);
      const float bias = fc2b[wrow];
      short4v pk;
      #pragma unroll
      for (int r = 0; r < 4; r++) pk[r] = f2s(acc[r] + bias);
      *(short4v*)(s_at + wrow*68 + row0) = pk;   // [c][token], 4 consecutive tokens
    }
  }
  __syncthreads();

  // ---------------- writeout: fp32 residual add, window merge ----
  #pragma unroll
  for (int it = 0; it < 6; it++){
    const int idx4 = it*256 + tid;
    const int c = idx4 >> 4, r = idx4 & 15;
    const int irow = r >> 1, j0 = (r & 1) * 4;
    const int t0 = irow*8 + j0;
    const short4v pv = *(const short4v*)(s_at + c*68 + t0);
    const size_t g = base + (size_t)c*65536 + irow*256 + j0;
    const float4 xv = *(const float4*)(x + g);
    float4 ov;
    ov.x = xv.x + s2f(pv[0]);
    ov.y = xv.y + s2f(pv[1]);
    ov.z = xv.z + s2f(pv[2]);
    ov.w = xv.w + s2f(pv[3]);
    *(float4*)(out + g) = ov;
  }
}

extern "C" void kernel_launch(void* const* d_in, const int* in_sizes, int n_in,
                              void* d_out, int out_size, void* d_ws, size_t ws_size,
                              hipStream_t stream) {
  const float* x     = (const float*)d_in[0];
  const float* qkvw  = (const float*)d_in[1];
  const float* qkvb  = (const float*)d_in[2];
  const float* projw = (const float*)d_in[3];
  const float* projb = (const float*)d_in[4];
  const float* rpb   = (const float*)d_in[5];
  const float* n1g   = (const float*)d_in[6];
  const float* n1b   = (const float*)d_in[7];
  const float* n2g   = (const float*)d_in[8];
  const float* n2b   = (const float*)d_in[9];
  const float* fc1w  = (const float*)d_in[10];
  const float* fc1b  = (const float*)d_in[11];
  const float* fc2w  = (const float*)d_in[12];
  const float* fc2b  = (const float*)d_in[13];
  float* out = (float*)d_out;

  swin_block_kernel<<<dim3(8192), dim3(TPB), 0, stream>>>(
      x, qkvw, qkvb, projw, projb, rpb,
      n1g, n1b, n2g, n2b, fc1w, fc1b, fc2w, fc2b, out);
}